// Round 10
// baseline (393.622 us; speedup 1.0000x reference)
//
#include <hip/hip_runtime.h>
#include <hip/hip_bf16.h>

#define B_   32
#define N_   4096
#define D_   768
#define HID_ 256

#define SX 64.0f
#define SW 1024.0f
#define INV_S (1.0f / 65536.0f)

typedef unsigned long long ull;
typedef _Float16 half8 __attribute__((ext_vector_type(8)));
typedef _Float16 half4 __attribute__((ext_vector_type(4)));
typedef float f32x16 __attribute__((ext_vector_type(16)));

// ---------------- Kernel P: fused prep: W-split (blocks 0..95) + label proj (96..127)
// Whi/Wlo layout: [96 chunks][256 hid][8 k] f16 — the 32x32x16 A-fragment order.
__global__ __launch_bounds__(256) void prep_kernel(
    const float* __restrict__ W1, _Float16* __restrict__ whi,
    _Float16* __restrict__ wlo, const float* __restrict__ lc,
    const float* __restrict__ Wp, const float* __restrict__ bp,
    float* __restrict__ lbl_n) {
  if (blockIdx.x < 96) {
    int c = blockIdx.x;
    int h = threadIdx.x;
    half8 vh, vl;
#pragma unroll
    for (int j = 0; j < 8; ++j) {
      float w = W1[(size_t)(c * 8 + j) * 256 + h] * SW;
      _Float16 hi = (_Float16)w;
      vh[j] = hi;
      vl[j] = (_Float16)(w - (float)hi);
    }
    *(half8*)&whi[((size_t)c * 256 + h) * 8] = vh;
    *(half8*)&wlo[((size_t)c * 256 + h) * 8] = vl;
    return;
  }
  int b = blockIdx.x - 96;
  int t = threadIdx.x;
  __shared__ float s_lc[128];
  __shared__ float s_out[768];
  __shared__ float s_red[4];

  if (t < 128) s_lc[t] = lc[b * 128 + t];
  __syncthreads();

  float sumsq = 0.f;
  for (int d = t; d < D_; d += 256) {
    float acc = bp[d];
    for (int k = 0; k < 128; ++k) acc += s_lc[k] * Wp[k * D_ + d];
    s_out[d] = acc;
    sumsq += acc * acc;
  }
  for (int off = 32; off >= 1; off >>= 1) sumsq += __shfl_xor(sumsq, off);
  if ((t & 63) == 0) s_red[t >> 6] = sumsq;
  __syncthreads();
  float tot = s_red[0] + s_red[1] + s_red[2] + s_red[3];
  float inv = 1.f / fmaxf(sqrtf(tot), 1e-12f);
  for (int d = t; d < D_; d += 256) lbl_n[b * D_ + d] = s_out[d] * inv;
}

// ---------------- Kernel B: split-f16 MFMA score kernel, v13 ----------------
// m201-style phase discipline. Block: 8 waves (512 thr) = 128 patches x 256 hid.
// Wave (hh=w>>1, pg=w&1): hid quarter hh*64 (mt=2), patches pg*64 (bt=2); acc 64 VGPR.
// W A-frags DIRECT L2->regs, 3 rotating sets, issued 2 phases ahead.
// X: f16 hi/lo split on staging path, small LDS dbuf, reg prefetch depth 2.
// Per phase: {issue W(S+2), issue X(S+2), ds_read B(S), vmcnt(5), split X(S+1),
// lgkm(0)} -> ONE s_barrier -> setprio(1) 12 MFMA setprio(0). MFMA after barrier,
// fully register-fed; vmcnt never drained to 0 in the loop.
__global__ __launch_bounds__(512, 2) void score13_kernel(
    const float* __restrict__ X, const _Float16* __restrict__ Whi,
    const _Float16* __restrict__ Wlo, const float* __restrict__ b1,
    const float* __restrict__ W2, const float* __restrict__ b2,
    const float* __restrict__ lbl_n, float* __restrict__ scores) {
  __shared__ __align__(16) _Float16 sB[2][2][2][128][8];  // [buf][hl][k8][row][8] 16KB
  __shared__ __align__(16) float sLbl[768];
  __shared__ float sB1[256], sW2[256];
  __shared__ float sVs[4][128];
  __shared__ float sLsc[128];

  const int t  = threadIdx.x;
  const int w  = t >> 6;
  const int l  = t & 63;
  const int l5 = l >> 5;
  const int ln = l & 31;
  const int hh = w >> 1;   // hid quarter
  const int pg = w & 1;    // patch half
  const int pb = blockIdx.x * 128;
  const int batch = pb >> 12;

  // staging role: thread t owns patch row r, k-quarter kq (4 floats/stage)
  const int r  = t >> 2;
  const int kq = t & 3;
  const float* xbase = X + (size_t)(pb + r) * D_ + kq * 4;

  const half8* gWh = (const half8*)Whi;
  const half8* gWl = (const half8*)Wlo;
  const int hidb = hh * 64 + ln;  // + mt*32

  f32x16 acc[2][2];
#pragma unroll
  for (int mt = 0; mt < 2; ++mt)
#pragma unroll
    for (int bt = 0; bt < 2; ++bt)
#pragma unroll
      for (int q = 0; q < 16; ++q) acc[mt][bt][q] = 0.f;

  float sq = 0.f, dt = 0.f;
  half8 wH[3][2], wL[3][2];   // 3 rotating W frag sets (static-indexed via unroll)
  float4 xr[2];               // X reg ping-pong (static-indexed via unroll)

#define SPLIT(TB, XV, SIDX)                                                    \
  {                                                                            \
    half4 nh, nl;                                                              \
    const float4 lv = *(const float4*)&sLbl[(SIDX) * 16 + kq * 4];             \
    _Pragma("unroll")                                                          \
    for (int j = 0; j < 4; ++j) {                                              \
      float xv = (&(XV).x)[j];                                                 \
      sq += xv * xv;                                                           \
      dt += xv * (&lv.x)[j];                                                   \
      float xs = xv * SX;                                                      \
      _Float16 hi = (_Float16)xs;                                              \
      nh[j] = hi;                                                              \
      nl[j] = (_Float16)(xs - (float)hi);                                      \
    }                                                                          \
    *(half4*)&sB[TB][0][kq >> 1][r][(kq & 1) * 4] = nh;                        \
    *(half4*)&sB[TB][1][kq >> 1][r][(kq & 1) * 4] = nl;                        \
  }

#define PHASE(S, CSET, PSET, CBUF)                                             \
  {                                                                            \
    const int S_ = (S);                                                        \
    /* issue W(S+2) -> set PSET (clamped for tail; keeps vmcnt invariant) */   \
    {                                                                          \
      const int sw = (S_ + 2 > 47) ? 47 : S_ + 2;                              \
      const int cc = sw * 2 + l5;                                              \
      wH[PSET][0] = gWh[cc * 256 + hidb];                                      \
      wH[PSET][1] = gWh[cc * 256 + hidb + 32];                                 \
      wL[PSET][0] = gWl[cc * 256 + hidb];                                      \
      wL[PSET][1] = gWl[cc * 256 + hidb + 32];                                 \
    }                                                                          \
    /* issue X(S+2) -> xr[CBUF] (just freed) */                                \
    {                                                                          \
      const int sx = (S_ + 2 > 47) ? 47 : S_ + 2;                              \
      xr[CBUF] = *(const float4*)(xbase + sx * 16);                            \
    }                                                                          \
    /* ds_read B frags(S) */                                                   \
    half8 bh0 = *(const half8*)&sB[CBUF][0][l5][pg * 64 + ln][0];              \
    half8 bl0 = *(const half8*)&sB[CBUF][1][l5][pg * 64 + ln][0];              \
    half8 bh1 = *(const half8*)&sB[CBUF][0][l5][pg * 64 + 32 + ln][0];         \
    half8 bl1 = *(const half8*)&sB[CBUF][1][l5][pg * 64 + 32 + ln][0];         \
    __builtin_amdgcn_sched_barrier(0);                                         \
    /* counted drain: completes W(S+1) + X(S+1); keeps the 5 just issued */    \
    asm volatile("s_waitcnt vmcnt(5)" ::: "memory");                           \
    __builtin_amdgcn_sched_barrier(0);                                         \
    if (S_ < 47) { SPLIT((CBUF) ^ 1, xr[(CBUF) ^ 1], S_ + 1) }                 \
    asm volatile("s_waitcnt lgkmcnt(0)" ::: "memory");                         \
    __builtin_amdgcn_sched_barrier(0);                                         \
    __builtin_amdgcn_s_barrier();                                              \
    /* pure register-fed MFMA cluster */                                       \
    __builtin_amdgcn_s_setprio(1);                                             \
    acc[0][0] = __builtin_amdgcn_mfma_f32_32x32x16_f16(wH[CSET][0], bh0, acc[0][0], 0, 0, 0); \
    acc[1][0] = __builtin_amdgcn_mfma_f32_32x32x16_f16(wH[CSET][1], bh0, acc[1][0], 0, 0, 0); \
    acc[0][1] = __builtin_amdgcn_mfma_f32_32x32x16_f16(wH[CSET][0], bh1, acc[0][1], 0, 0, 0); \
    acc[1][1] = __builtin_amdgcn_mfma_f32_32x32x16_f16(wH[CSET][1], bh1, acc[1][1], 0, 0, 0); \
    acc[0][0] = __builtin_amdgcn_mfma_f32_32x32x16_f16(wH[CSET][0], bl0, acc[0][0], 0, 0, 0); \
    acc[1][0] = __builtin_amdgcn_mfma_f32_32x32x16_f16(wH[CSET][1], bl0, acc[1][0], 0, 0, 0); \
    acc[0][1] = __builtin_amdgcn_mfma_f32_32x32x16_f16(wH[CSET][0], bl1, acc[0][1], 0, 0, 0); \
    acc[1][1] = __builtin_amdgcn_mfma_f32_32x32x16_f16(wH[CSET][1], bl1, acc[1][1], 0, 0, 0); \
    acc[0][0] = __builtin_amdgcn_mfma_f32_32x32x16_f16(wL[CSET][0], bh0, acc[0][0], 0, 0, 0); \
    acc[1][0] = __builtin_amdgcn_mfma_f32_32x32x16_f16(wL[CSET][1], bh0, acc[1][0], 0, 0, 0); \
    acc[0][1] = __builtin_amdgcn_mfma_f32_32x32x16_f16(wL[CSET][0], bh1, acc[0][1], 0, 0, 0); \
    acc[1][1] = __builtin_amdgcn_mfma_f32_32x32x16_f16(wL[CSET][1], bh1, acc[1][1], 0, 0, 0); \
    __builtin_amdgcn_s_setprio(0);                                             \
  }

  // ---- prologue ----
  for (int i = t; i < D_; i += 512) sLbl[i] = lbl_n[batch * D_ + i];
  if (t < 256) { sB1[t] = b1[t]; sW2[t] = W2[t]; }
  {  // W(0) -> set0, W(1) -> set1
    wH[0][0] = gWh[l5 * 256 + hidb];        wH[0][1] = gWh[l5 * 256 + hidb + 32];
    wL[0][0] = gWl[l5 * 256 + hidb];        wL[0][1] = gWl[l5 * 256 + hidb + 32];
    const int c1 = 2 + l5;
    wH[1][0] = gWh[c1 * 256 + hidb];        wH[1][1] = gWh[c1 * 256 + hidb + 32];
    wL[1][0] = gWl[c1 * 256 + hidb];        wL[1][1] = gWl[c1 * 256 + hidb + 32];
  }
  xr[0] = *(const float4*)(xbase);          // X(0)
  xr[1] = *(const float4*)(xbase + 16);     // X(1)
  __syncthreads();                          // full drain once; sLbl ready

  SPLIT(0, xr[0], 0)                        // stage 0 -> buf0; xr[0] freed
  asm volatile("s_waitcnt lgkmcnt(0)" ::: "memory");
  __builtin_amdgcn_s_barrier();             // sB[0] visible

  // ---- main loop: 48 phases, unrolled x6 (lcm of 3 W-sets x 2 buffers) ----
  for (int s6 = 0; s6 < 48; s6 += 6) {
    PHASE(s6 + 0, 0, 2, 0)
    PHASE(s6 + 1, 1, 0, 1)
    PHASE(s6 + 2, 2, 1, 0)
    PHASE(s6 + 3, 0, 2, 1)
    PHASE(s6 + 4, 1, 0, 0)
    PHASE(s6 + 5, 2, 1, 1)
  }
#undef PHASE
#undef SPLIT

  // ---- epilogue ----
  sq += __shfl_xor(sq, 1);  dt += __shfl_xor(dt, 1);
  sq += __shfl_xor(sq, 2);  dt += __shfl_xor(dt, 2);
  if ((t & 3) == 0) sLsc[r] = dt / fmaxf(sqrtf(sq), 1e-12f);

  float vsb[2] = {0.f, 0.f};
#pragma unroll
  for (int mt = 0; mt < 2; ++mt) {
#pragma unroll
    for (int rq = 0; rq < 4; ++rq) {
      const int hb = hh * 64 + mt * 32 + rq * 8 + l5 * 4;
      const float4 b1v = *(const float4*)&sB1[hb];
      const float4 w2v = *(const float4*)&sW2[hb];
#pragma unroll
      for (int j = 0; j < 4; ++j) {
        float h0 = acc[mt][0][rq * 4 + j] * INV_S + (&b1v.x)[j];
        float h1 = acc[mt][1][rq * 4 + j] * INV_S + (&b1v.x)[j];
        vsb[0] += fmaxf(h0, 0.f) * (&w2v.x)[j];
        vsb[1] += fmaxf(h1, 0.f) * (&w2v.x)[j];
      }
    }
  }
  vsb[0] += __shfl_xor(vsb[0], 32);
  vsb[1] += __shfl_xor(vsb[1], 32);
  if (l < 32) {
    sVs[hh][pg * 64 + l]      = vsb[0];
    sVs[hh][pg * 64 + 32 + l] = vsb[1];
  }
  __syncthreads();

  if (t < 128) {
    float vst = sVs[0][t] + sVs[1][t] + sVs[2][t] + sVs[3][t] + b2[0];
    scores[pb + t] = 0.4f * vst + 0.6f * sLsc[t];
  }
}

// ---------------- Kernel C: per-batch exact top-K, cached wave-max tournament --
__global__ __launch_bounds__(256) void topk3_kernel(
    const float* __restrict__ scores, int* __restrict__ out_idx,
    float* __restrict__ out_idx_f, int K) {
  int b = blockIdx.x;
  int t = threadIdx.x;
  int wv = t >> 6, l = t & 63;
  __shared__ ull swm[4];

  ull keys[16];
#pragma unroll
  for (int j = 0; j < 16; ++j) {
    int i = (j << 8) + t;  // coalesced
    float s = scores[(b << 12) + i];
    unsigned u = __float_as_uint(s);
    u = (u & 0x80000000u) ? ~u : (u | 0x80000000u);
    keys[j] = ((ull)u << 32) | (unsigned)(4095 - i);  // tie -> lower index wins
  }
  ull cur = 0;
#pragma unroll
  for (int j = 0; j < 16; ++j) cur = keys[j] > cur ? keys[j] : cur;

  {  // initial per-wave reduce
    ull wb = cur;
#pragma unroll
    for (int off = 1; off < 64; off <<= 1) {
      ull o = __shfl_xor(wb, off);
      wb = o > wb ? o : wb;
    }
    if (l == 0) swm[wv] = wb;
  }
  __syncthreads();

  for (int sel = 0; sel < K; ++sel) {
    ull m0 = swm[0] > swm[1] ? swm[0] : swm[1];
    ull m1 = swm[2] > swm[3] ? swm[2] : swm[3];
    ull best = m0 > m1 ? m0 : m1;
    if (t == 0) {
      int id = 4095 - (int)(unsigned)(best & 0xFFFFFFFFull);
      out_idx[b * K + sel] = id;
      out_idx_f[b * K + sel] = (float)id;
    }
    if (swm[wv] == best) {  // only the owning wave re-reduces
      if (cur == best) {
        cur = 0;
#pragma unroll
        for (int j = 0; j < 16; ++j)
          cur = (keys[j] < best && keys[j] > cur) ? keys[j] : cur;
      }
      ull wb = cur;
#pragma unroll
      for (int off = 1; off < 64; off <<= 1) {
        ull o = __shfl_xor(wb, off);
        wb = o > wb ? o : wb;
      }
      if (l == 0) swm[wv] = wb;
    }
    __syncthreads();
  }
}

// ---------------- Kernel D: gather ----------------
__global__ __launch_bounds__(192) void gather_kernel(
    const float* __restrict__ feats, const int* __restrict__ idx,
    float* __restrict__ out_feats, int K) {
  int i = blockIdx.x;
  int b = blockIdx.y;
  int id = idx[b * K + i];
  const float4* src = (const float4*)&feats[((size_t)b * N_ + id) * D_];
  float4* dst = (float4*)&out_feats[((size_t)b * K + i) * D_];
  dst[threadIdx.x] = src[threadIdx.x];
}

extern "C" void kernel_launch(void* const* d_in, const int* in_sizes, int n_in,
                              void* d_out, int out_size, void* d_ws, size_t ws_size,
                              hipStream_t stream) {
  const float* feats = (const float*)d_in[0];
  const float* lc    = (const float*)d_in[1];
  const float* W1    = (const float*)d_in[2];
  const float* b1    = (const float*)d_in[3];
  const float* W2    = (const float*)d_in[4];
  const float* b2    = (const float*)d_in[5];
  const float* Wp    = (const float*)d_in[6];
  const float* bp    = (const float*)d_in[7];
  int K = out_size / (B_ * (D_ + 1));  // 192

  float* ws_f    = (float*)d_ws;
  float* lbl_n   = ws_f;                              // 32*768
  float* scoresv = ws_f + B_ * D_;                    // 32*4096
  int*   topidx  = (int*)(ws_f + B_ * D_ + B_ * N_);  // 32*192
  size_t off = (size_t)B_ * D_ + (size_t)B_ * N_ + B_ * 256;
  off = (off + 3) & ~(size_t)3;
  _Float16* whi = (_Float16*)(ws_f + off);            // 96*256*8 halves
  _Float16* wlo = whi + (size_t)96 * 256 * 8;

  float* out_f     = (float*)d_out;
  float* out_idx_f = out_f + (size_t)B_ * K * D_;

  prep_kernel<<<128, 256, 0, stream>>>(W1, whi, wlo, lc, Wp, bp, lbl_n);
  score13_kernel<<<(B_ * N_) / 128, 512, 0, stream>>>(feats, whi, wlo, b1, W2, b2,
                                                      lbl_n, scoresv);
  topk3_kernel<<<B_, 256, 0, stream>>>(scoresv, topidx, out_idx_f, K);
  gather_kernel<<<dim3(K, B_), 192, 0, stream>>>(feats, topidx, out_f, K);
}